// Round 1
// baseline (1874.844 us; speedup 1.0000x reference)
//
#include <hip/hip_runtime.h>

#define K_CLUS 100
#define D_FEAT 64

// ---------------------------------------------------------------------------
// Kernel 1: one pass over the 512MB of points.
//   lane d of each wave owns feature d. Per 64-point chunk:
//     - wave loads 64 cluster ids (coalesced), broadcasts via v_readlane
//     - per point: one coalesced 256B load, two ds_add_f32 (sum, sumsq)
//   LDS layout s[c*64+lane]: bank = lane%32 -> 2 lanes/bank (free).
// ---------------------------------------------------------------------------
__global__ __launch_bounds__(512) void accum_kernel(
    const float* __restrict__ data, const int* __restrict__ clus,
    float* __restrict__ gsum, float* __restrict__ gq, float* __restrict__ gcnt,
    int n)
{
    __shared__ float s_sum[K_CLUS * D_FEAT];
    __shared__ float s_q[K_CLUS * D_FEAT];
    __shared__ float s_cnt[K_CLUS];

    const int tid = threadIdx.x;
    for (int i = tid; i < K_CLUS * D_FEAT; i += blockDim.x) {
        s_sum[i] = 0.0f;
        s_q[i]   = 0.0f;
    }
    if (tid < K_CLUS) s_cnt[tid] = 0.0f;
    __syncthreads();

    const int lane            = tid & 63;
    const int wave_in_block   = tid >> 6;
    const int waves_per_block = blockDim.x >> 6;
    const long long gw     = (long long)blockIdx.x * waves_per_block + wave_in_block;
    const long long nwaves = (long long)gridDim.x * waves_per_block;
    const long long nchunks = n >> 6;   // N = 2,000,000 is divisible by 64

    for (long long ch = gw; ch < nchunks; ch += nwaves) {
        const long long base = ch << 6;
        const int cid = clus[base + lane];           // coalesced 256B (int32)
        atomicAdd(&s_cnt[cid], 1.0f);                // 1 ds instr / 64 points
        const float* dp = data + (size_t)base * D_FEAT + lane;
        #pragma unroll 16
        for (int t = 0; t < 64; ++t) {
            const int c = __builtin_amdgcn_readlane(cid, t);  // SGPR broadcast
            const float x = dp[(size_t)t * D_FEAT];           // coalesced 256B
            atomicAdd(&s_sum[c * D_FEAT + lane], x);
            atomicAdd(&s_q[c * D_FEAT + lane], x * x);
        }
    }

    // tail (none for N=2e6, kept for generality)
    if (gw == 0 && (n & 63)) {
        for (long long i = nchunks << 6; i < n; ++i) {
            const int c = clus[i];
            const float x = data[(size_t)i * D_FEAT + lane];
            atomicAdd(&s_sum[c * D_FEAT + lane], x);
            atomicAdd(&s_q[c * D_FEAT + lane], x * x);
            if (lane == 0) atomicAdd(&s_cnt[c], 1.0f);
        }
    }

    __syncthreads();
    for (int i = tid; i < K_CLUS * D_FEAT; i += blockDim.x) {
        unsafeAtomicAdd(&gsum[i], s_sum[i]);   // native global_atomic_add_f32
        unsafeAtomicAdd(&gq[i],   s_q[i]);
    }
    if (tid < K_CLUS) unsafeAtomicAdd(&gcnt[tid], s_cnt[tid]);
}

// ---------------------------------------------------------------------------
// Kernel 2: K=100 finalize. One block, 16 waves.
//   Si via   T_k = Q_k - 2 A.S + c_k ||A||^2
//   A stored transposed At[d][k] in LDS so the j-sweep in phase 2 is
//   bank-conflict-free; At[d][i] is a same-address broadcast.
// ---------------------------------------------------------------------------
__global__ __launch_bounds__(1024) void finalize_kernel(
    const float* __restrict__ gsum, const float* __restrict__ gq,
    const float* __restrict__ gcnt, float* __restrict__ out)
{
    __shared__ float At[D_FEAT * K_CLUS];   // [d][k]
    __shared__ float Si[K_CLUS];
    __shared__ float rowmax[K_CLUS];

    const int tid  = threadIdx.x;
    const int lane = tid & 63;
    const int w    = tid >> 6;              // 16 waves

    // phase 1: centroids + Si
    for (int k = w; k < K_CLUS; k += 16) {
        const float s      = gsum[k * D_FEAT + lane];
        const float q      = gq[k * D_FEAT + lane];
        const float cnt    = gcnt[k];
        const float counts = cnt + 1.0f;
        const float a      = (0.001f + s) / counts;
        At[lane * K_CLUS + k] = a;
        float r = q - 2.0f * a * s + cnt * a * a;
        for (int off = 32; off; off >>= 1) r += __shfl_xor(r, off, 64);
        if (lane == 0) Si[k] = sqrtf((0.001f + r) / counts);
    }
    __syncthreads();

    // phase 2: row-wise max of Rij
    for (int i = w; i < K_CLUS; i += 16) {
        const float si = Si[i];
        const int j1 = lane;        // 0..63, all < K
        const int j2 = lane + 64;   // 64..127, valid if < K
        float d1 = 0.0f, d2 = 0.0f;
        for (int d = 0; d < D_FEAT; ++d) {
            const float ai = At[d * K_CLUS + i];           // broadcast
            const float t1 = ai - At[d * K_CLUS + j1];
            d1 += t1 * t1;
            if (j2 < K_CLUS) {
                const float t2 = ai - At[d * K_CLUS + j2];
                d2 += t2 * t2;
            }
        }
        float r1 = (j1 != i) ? (si + Si[j1]) / sqrtf(d1) : 0.0f;
        float r2 = (j2 < K_CLUS && j2 != i) ? (si + Si[j2]) / sqrtf(d2) : 0.0f;
        float m = fmaxf(r1, r2);
        for (int off = 32; off; off >>= 1) m = fmaxf(m, __shfl_xor(m, off, 64));
        if (lane == 0) rowmax[i] = m;
    }
    __syncthreads();

    // phase 3: sum of row maxima / K
    if (tid < 64) {
        float v = rowmax[tid];
        if (tid + 64 < K_CLUS) v += rowmax[tid + 64];
        for (int off = 32; off; off >>= 1) v += __shfl_xor(v, off, 64);
        if (tid == 0) out[0] = v / (float)K_CLUS;
    }
}

// ---------------------------------------------------------------------------
extern "C" void kernel_launch(void* const* d_in, const int* in_sizes, int n_in,
                              void* d_out, int out_size, void* d_ws, size_t ws_size,
                              hipStream_t stream)
{
    const float* data = (const float*)d_in[0];
    const int*   clus = (const int*)d_in[1];
    float*       out  = (float*)d_out;
    const int    n    = in_sizes[1];

    float* gsum = (float*)d_ws;                    // [K][64]
    float* gq   = gsum + K_CLUS * D_FEAT;          // [K][64]
    float* gcnt = gq   + K_CLUS * D_FEAT;          // [K]

    hipMemsetAsync(d_ws, 0, (size_t)(2 * K_CLUS * D_FEAT + K_CLUS) * sizeof(float), stream);

    // 3 blocks/CU (LDS-limited: 51.6KB/block) x 256 CUs
    accum_kernel<<<768, 512, 0, stream>>>(data, clus, gsum, gq, gcnt, n);
    finalize_kernel<<<1, 1024, 0, stream>>>(gsum, gq, gcnt, out);
}

// Round 2
// 698.783 us; speedup vs baseline: 2.6830x; 2.6830x over previous
//
#include <hip/hip_runtime.h>

#define K_CLUS 100
#define D_FEAT 64
#define TILE   4096
#define BLOCK  512          // 8 waves
#define NWAVES 8
#define PER_T  (TILE / BLOCK)   // ids per thread = 8

// ---------------------------------------------------------------------------
// Kernel 1: one pass over the points, tile-local counting sort by cluster,
// register run-accumulation, one LDS fp-atomic flush per cluster RUN.
//   lane d of a wave owns feature d (all loads are coalesced 256B rows).
// ---------------------------------------------------------------------------
__global__ __launch_bounds__(BLOCK) void accum_kernel(
    const float* __restrict__ data, const int* __restrict__ clus,
    float* __restrict__ gsum, float* __restrict__ gqs, float* __restrict__ gcnt,
    int n)
{
    __shared__ float s_sum[K_CLUS * D_FEAT];  // 25.6 KB  per-feature sums
    __shared__ float s_qs[K_CLUS];            // scalar sum of squares
    __shared__ int   s_idx[TILE];             // 16 KB    (c<<12 | loc), loc<4096
    __shared__ int   s_hist[K_CLUS];
    __shared__ int   s_pos[K_CLUS];

    const int tid  = threadIdx.x;
    const int lane = tid & 63;
    const int w    = tid >> 6;

    const long long tile_start = (long long)blockIdx.x * TILE;
    const int ts = (int)min((long long)TILE, (long long)n - tile_start);

    for (int i = tid; i < K_CLUS * D_FEAT; i += BLOCK) s_sum[i] = 0.0f;
    if (tid < K_CLUS) { s_qs[tid] = 0.0f; s_hist[tid] = 0; }
    __syncthreads();

    // ---- phase A: load ids, histogram (int LDS atomics) ----
    int myc[PER_T];
    #pragma unroll
    for (int r = 0; r < PER_T; ++r) {
        const int loc = r * BLOCK + tid;
        int c = 0;
        if (loc < ts) {
            c = clus[tile_start + loc];
            atomicAdd(&s_hist[c], 1);
        }
        myc[r] = c;
    }
    __syncthreads();

    // ---- phase B: exclusive prefix over 100 bins (wave 0, shfl scan) ----
    if (w == 0) {
        int v0 = s_hist[lane];                       // bins 0..63
        int inc0 = v0;
        #pragma unroll
        for (int d = 1; d < 64; d <<= 1) {
            int t = __shfl_up(inc0, d, 64);
            if (lane >= d) inc0 += t;
        }
        s_pos[lane] = inc0 - v0;                     // exclusive
        const int total0 = __shfl(inc0, 63, 64);
        int v1 = (lane < K_CLUS - 64) ? s_hist[64 + lane] : 0;
        int inc1 = v1;
        #pragma unroll
        for (int d = 1; d < 64; d <<= 1) {
            int t = __shfl_up(inc1, d, 64);
            if (lane >= d) inc1 += t;
        }
        if (lane < K_CLUS - 64) s_pos[64 + lane] = total0 + inc1 - v1;
    }
    __syncthreads();

    // ---- phase C: scatter sorted entries ----
    #pragma unroll
    for (int r = 0; r < PER_T; ++r) {
        const int loc = r * BLOCK + tid;
        if (loc < ts) {
            const int c = myc[r];
            const int p = atomicAdd(&s_pos[c], 1);
            s_idx[p] = (c << 12) | loc;
        }
    }
    __syncthreads();

    // ---- phase D: run-accumulate. wave w owns sorted range [sb, se) ----
    const int seg = (ts + NWAVES - 1) / NWAVES;
    const int sb  = w * seg;
    const int se  = min(sb + seg, ts);

    float sacc = 0.0f, qacc = 0.0f;
    int run_c = -1;

    auto flush = [&]() {
        atomicAdd(&s_sum[run_c * D_FEAT + lane], sacc);
        float qq = qacc;
        #pragma unroll
        for (int off = 32; off; off >>= 1) qq += __shfl_xor(qq, off, 64);
        if (lane == 0) atomicAdd(&s_qs[run_c], qq);
        sacc = 0.0f; qacc = 0.0f;
    };

    for (int b = sb; b < se; b += 64) {
        const int m = min(64, se - b);
        const int e_lane = s_idx[b + ((lane < m) ? lane : (m - 1))];
        if (m == 64) {
            #pragma unroll
            for (int g = 0; g < 8; ++g) {
                int   ce[8];
                float xv[8];
                #pragma unroll
                for (int j = 0; j < 8; ++j) {   // batch 8 independent loads
                    const int e = __builtin_amdgcn_readlane(e_lane, g * 8 + j);
                    ce[j] = e >> 12;
                    xv[j] = data[((size_t)tile_start + (e & 4095)) * D_FEAT + lane];
                }
                #pragma unroll
                for (int j = 0; j < 8; ++j) {
                    if (ce[j] != run_c) {        // wave-uniform branch
                        if (run_c >= 0) flush();
                        run_c = ce[j];
                    }
                    sacc += xv[j];
                    qacc += xv[j] * xv[j];
                }
            }
        } else {
            for (int t = 0; t < m; ++t) {
                const int e = __builtin_amdgcn_readlane(e_lane, t);
                const int c = e >> 12;
                if (c != run_c) {
                    if (run_c >= 0) flush();
                    run_c = c;
                }
                const float x = data[((size_t)tile_start + (e & 4095)) * D_FEAT + lane];
                sacc += x;
                qacc += x * x;
            }
        }
    }
    if (run_c >= 0) flush();

    // ---- phase E: block flush to global (native f32 atomics) ----
    __syncthreads();
    for (int i = tid; i < K_CLUS * D_FEAT; i += BLOCK) {
        const float v = s_sum[i];
        if (v != 0.0f) unsafeAtomicAdd(&gsum[i], v);
    }
    if (tid < K_CLUS) {
        if (s_qs[tid] != 0.0f) unsafeAtomicAdd(&gqs[tid], s_qs[tid]);
        if (s_hist[tid] != 0)  unsafeAtomicAdd(&gcnt[tid], (float)s_hist[tid]);
    }
}

// ---------------------------------------------------------------------------
// Kernel 2: K=100 finalize. One block, 16 waves.
//   Si via T_k = Q_k - 2 A.S + c_k ||A||^2  (Q_k is a scalar now)
// ---------------------------------------------------------------------------
__global__ __launch_bounds__(1024) void finalize_kernel(
    const float* __restrict__ gsum, const float* __restrict__ gqs,
    const float* __restrict__ gcnt, float* __restrict__ out)
{
    __shared__ float At[D_FEAT * K_CLUS];   // [d][k]
    __shared__ float Si[K_CLUS];
    __shared__ float rowmax[K_CLUS];

    const int tid  = threadIdx.x;
    const int lane = tid & 63;
    const int w    = tid >> 6;              // 16 waves

    // phase 1: centroids + Si
    for (int k = w; k < K_CLUS; k += 16) {
        const float s      = gsum[k * D_FEAT + lane];
        const float cnt    = gcnt[k];
        const float counts = cnt + 1.0f;
        const float a      = (0.001f + s) / counts;
        At[lane * K_CLUS + k] = a;
        float r = cnt * a * a - 2.0f * a * s;
        #pragma unroll
        for (int off = 32; off; off >>= 1) r += __shfl_xor(r, off, 64);
        if (lane == 0) Si[k] = sqrtf((0.001f + gqs[k] + r) / counts);
    }
    __syncthreads();

    // phase 2: row-wise max of Rij
    for (int i = w; i < K_CLUS; i += 16) {
        const float si = Si[i];
        const int j1 = lane;        // 0..63
        const int j2 = lane + 64;   // 64..127, valid if < K
        float d1 = 0.0f, d2 = 0.0f;
        for (int d = 0; d < D_FEAT; ++d) {
            const float ai = At[d * K_CLUS + i];           // broadcast
            const float t1 = ai - At[d * K_CLUS + j1];
            d1 += t1 * t1;
            if (j2 < K_CLUS) {
                const float t2 = ai - At[d * K_CLUS + j2];
                d2 += t2 * t2;
            }
        }
        float r1 = (j1 != i) ? (si + Si[j1]) / sqrtf(d1) : 0.0f;
        float r2 = (j2 < K_CLUS && j2 != i) ? (si + Si[j2]) / sqrtf(d2) : 0.0f;
        float m = fmaxf(r1, r2);
        #pragma unroll
        for (int off = 32; off; off >>= 1) m = fmaxf(m, __shfl_xor(m, off, 64));
        if (lane == 0) rowmax[i] = m;
    }
    __syncthreads();

    // phase 3: sum of row maxima / K
    if (tid < 64) {
        float v = rowmax[tid];
        if (tid + 64 < K_CLUS) v += rowmax[tid + 64];
        #pragma unroll
        for (int off = 32; off; off >>= 1) v += __shfl_xor(v, off, 64);
        if (tid == 0) out[0] = v / (float)K_CLUS;
    }
}

// ---------------------------------------------------------------------------
extern "C" void kernel_launch(void* const* d_in, const int* in_sizes, int n_in,
                              void* d_out, int out_size, void* d_ws, size_t ws_size,
                              hipStream_t stream)
{
    const float* data = (const float*)d_in[0];
    const int*   clus = (const int*)d_in[1];
    float*       out  = (float*)d_out;
    const int    n    = in_sizes[1];

    float* gsum = (float*)d_ws;                    // [K][64]
    float* gqs  = gsum + K_CLUS * D_FEAT;          // [K]
    float* gcnt = gqs + K_CLUS;                    // [K]

    hipMemsetAsync(d_ws, 0, (size_t)(K_CLUS * D_FEAT + 2 * K_CLUS) * sizeof(float), stream);

    const int ntiles = (n + TILE - 1) / TILE;      // 489 for N=2e6
    accum_kernel<<<ntiles, BLOCK, 0, stream>>>(data, clus, gsum, gqs, gcnt, n);
    finalize_kernel<<<1, 1024, 0, stream>>>(gsum, gqs, gcnt, out);
}